// Round 10
// baseline (127.364 us; speedup 1.0000x reference)
//
#include <hip/hip_runtime.h>
#include <math.h>

// B=2, HD=4, H=W=128, KSIZE=7 (K=49), NSP=9, S=64
#define BN   2
#define HDN  4
#define HN   128
#define WN   128
#define KS   7
#define KK   49
#define NSPN 9
#define TPB  256     // 4 waves; wave = 4 pixels x 4 heads x 4 k-slices
#define PIXSTR 60    // patch pixel stride (dwords)
#define PBUF (4 * PIXSTR)   // 240 dwords per plane buffer (4 patches)

// Compiler-only memory fence (v8-validated discipline for barrier-free
// cross-lane LDS reuse; emits nothing).
#define CFENCE() asm volatile("" ::: "memory")

// v12: k-split x4. v11 proved gather latency is hidden (depth-3 null); the
// residual ~12us is un-fillable stall time with only 2 waves/SIMD (grid-
// capped: 1 lane per (pix,hd) unit fixes 2048 waves total). Split each unit
// across 4 lanes (lane s owns rows {2s,2s+1} of the 7x7; s3: row 6 + zero-
// weight dummies): 8192 waves -> ~20 resident waves/CU (VGPR-capped), ~4x
// shorter per-wave critical path. Bonus: attn/out become DIRECT coalesced
// register I/O (49 contiguous dwords per unit / 4 lanes) -- the entire LDS
// staging phase is deleted. Gather: 1 wide instr per sp per wave (4 patches
// x 14 lanes, v9 codegen, single named q). Softmax max + denominator are
// 4-lane butterflies (shfl_xor 1,2; bitwise-identical -> coef consistent).
__global__ __launch_bounds__(TPB, 4) void attn_rw12(
    const float* __restrict__ attn,
    const float* __restrict__ sims,
    const int*   __restrict__ sinds,
    float*       __restrict__ out)
{
    __shared__ __align__(16) float pbm[4][2 * PBUF];    // per-wave patch dbuf (7.7 KB)
    __shared__ int g_lds[4][40];                        // per-wave sinds (36 used)

    const int t    = threadIdx.x;
    const int lane = t & 63;
    const int wv   = t >> 6;
    const int bx   = blockIdx.x;
    const int wseg = bx & 7;                 // 8 x 16-pixel segments
    const int hh   = (bx >> 3) & 127;
    const int b    = bx >> 10;
    const int ww0  = wseg * 16 + wv * 4;     // wave's first absolute column

    const int u   = lane >> 2;               // unit 0..15
    const int s   = lane & 3;                // k-slice: rows {2s, 2s+1}
    const int pix = u >> 2;                  // 0..3
    const int hd  = u & 3;

    const float* simsB = sims + ((size_t)b << 20);
    int hs = hh - 3; hs = max(0, min(HN - KS, hs));
    const int dr = hh - hs;                  // 0..6, block-uniform

    float* pb = pbm[wv];
    int*   gl = g_lds[wv];

    // ---- sinds: 36 ints, one coalesced int4 round ----
    {
        const int* ssrc = sinds + ((b * HN + hh) * WN + ww0) * NSPN;
        if (lane < 9) {
            int4 sv;
            __builtin_memcpy(&sv, ssrc + lane * 4, 16);
            *(int4*)(gl + lane * 4) = sv;
        }
    }
    CFENCE();                                // gl published (cross-lane consumers)

    // ---- attn: DIRECT loads, lane owns k = s*14 + j (contiguous) ----
    const size_t hwk   = (size_t)HN * WN * KK;
    const size_t ubase = ((size_t)b * HDN + hd) * hwk
                       + (size_t)(hh * WN + ww0 + pix) * KK;
    const float* ap = attn + ubase + s * 14;

    float a[14];
    if (s < 3) {
        float4 x0, x1, x2; float2 x3;
        __builtin_memcpy(&x0, ap,      16);
        __builtin_memcpy(&x1, ap + 4,  16);
        __builtin_memcpy(&x2, ap + 8,  16);
        __builtin_memcpy(&x3, ap + 12,  8);
        a[0]=x0.x;  a[1]=x0.y;  a[2]=x0.z;  a[3]=x0.w;
        a[4]=x1.x;  a[5]=x1.y;  a[6]=x1.z;  a[7]=x1.w;
        a[8]=x2.x;  a[9]=x2.y;  a[10]=x2.z; a[11]=x2.w;
        a[12]=x3.x; a[13]=x3.y;
    } else {                                  // s3: row 6 only (7 real k)
        float4 x0; float2 x1;
        __builtin_memcpy(&x0, ap,     16);
        __builtin_memcpy(&x1, ap + 4,  8);
        float x2 = ap[6];
        a[0]=x0.x; a[1]=x0.y; a[2]=x0.z; a[3]=x0.w;
        a[4]=x1.x; a[5]=x1.y; a[6]=x2;
        #pragma unroll
        for (int j = 7; j < 14; ++j) a[j] = -1e30f;   // zero-weight dummies
    }

    // ---- wide-gather lane constants (4 patches in ONE instr) ----
    const int  grp   = min(lane / 14, 3);    // patch (=pixel) slot
    const int  cp    = lane - grp * 14;
    const int  grow  = min(cp >> 1, 6);      // row 0..6
    const int  ghalf = cp & 1;               // 0: cols 0-3, 1: cols 3-6
    const bool gact  = lane < 56;
    const int  wsg   = max(0, min(WN - KS, ww0 + grp - 3));
    const int  rowoff = (hs + grow) * WN + ghalf * 3;

    float4 q;                                // single named in-flight reg
#define ISSUE(sp) { \
        int g_ = gl[grp * NSPN + (sp)]; \
        if (gact) __builtin_memcpy(&q, simsB + ((size_t)g_ << 14) + rowoff + wsg, 16); }
#define GSTORE(buf) { \
        if (gact) *(float4*)(pb + (buf) * PBUF + grp * PIXSTR + grow * 8 + ghalf * 4) = q; }

    ISSUE(0)                                 // in flight under softmax

    // ---- softmax: local max/exp + 4-lane butterfly ----
    {
        float m0 = fmaxf(a[0], a[1]),  m1 = fmaxf(a[2], a[3]);
        float m2 = fmaxf(a[4], a[5]),  m3 = fmaxf(a[6], a[7]);
        m0 = fmaxf(m0, fmaxf(a[8], a[9]));
        m1 = fmaxf(m1, fmaxf(a[10], a[11]));
        m2 = fmaxf(m2, fmaxf(a[12], a[13]));
        float m = fmaxf(fmaxf(m0, m1), fmaxf(m2, m3));
        m = fmaxf(m, __shfl_xor(m, 1));
        m = fmaxf(m, __shfl_xor(m, 2));      // unit max, identical in 4 lanes
        #pragma unroll
        for (int j = 0; j < 14; ++j) a[j] = __expf(a[j] - m);   // dummies -> 0
    }

    GSTORE(0)

    // ---- compute-view constants ----
    const int prow0 = pix * PIXSTR + (2 * s) * 8;                  // row 2s quads
    const int prow1 = pix * PIXSTR + min(2 * s + 1, 6) * 8;        // row 2s+1 (s3: row6 again)
    const int wabs  = ww0 + pix;
    const int wsp   = max(0, min(WN - KS, wabs - 3));
    const int dc    = wabs - wsp;
    const int pioff = pix * PIXSTR + dr * 8 + dc + (dc > 3 ? 1 : 0);

    float acc[14];
    #pragma unroll
    for (int j = 0; j < 14; ++j) acc[j] = 0.0f;

    for (int sp = 0; sp < NSPN; ++sp) {
        const int buf = sp & 1;
        if (sp + 1 < NSPN) ISSUE(sp + 1)     // next plane in flight
        CFENCE();                            // RAW: gstore(prev)->reads; WAR: reads->gstore below

        const float* pp = pb + buf * PBUF;
        float4 p0 = *(const float4*)(pp + prow0);        // row r0 cols 0-3
        float4 p1 = *(const float4*)(pp + prow0 + 4);    // row r0 cols 3-6
        float4 p2 = *(const float4*)(pp + prow1);        // row r1 cols 0-3
        float4 p3 = *(const float4*)(pp + prow1 + 4);    // row r1 cols 3-6
        float pi  = pp[pioff];

        // partial denom over own 14 k (dummies contribute 0), 2-way chains
        float d0 = a[0] * p0.x, d1 = a[1] * p0.y;
        d0 = fmaf(a[2],  p0.z, d0); d1 = fmaf(a[3],  p0.w, d1);
        d0 = fmaf(a[4],  p1.y, d0); d1 = fmaf(a[5],  p1.z, d1);
        d0 = fmaf(a[6],  p1.w, d0); d1 = fmaf(a[7],  p2.x, d1);
        d0 = fmaf(a[8],  p2.y, d0); d1 = fmaf(a[9],  p2.z, d1);
        d0 = fmaf(a[10], p2.w, d0); d1 = fmaf(a[11], p3.y, d1);
        d0 = fmaf(a[12], p3.z, d0); d1 = fmaf(a[13], p3.w, d1);
        float d = d0 + d1;
        d += __shfl_xor(d, 1);
        d += __shfl_xor(d, 2);               // full unit denom, identical in 4 lanes

        float coef = pi * __builtin_amdgcn_rcpf(d + 1e-10f);

        acc[0]  = fmaf(coef, p0.x, acc[0]);  acc[1]  = fmaf(coef, p0.y, acc[1]);
        acc[2]  = fmaf(coef, p0.z, acc[2]);  acc[3]  = fmaf(coef, p0.w, acc[3]);
        acc[4]  = fmaf(coef, p1.y, acc[4]);  acc[5]  = fmaf(coef, p1.z, acc[5]);
        acc[6]  = fmaf(coef, p1.w, acc[6]);  acc[7]  = fmaf(coef, p2.x, acc[7]);
        acc[8]  = fmaf(coef, p2.y, acc[8]);  acc[9]  = fmaf(coef, p2.z, acc[9]);
        acc[10] = fmaf(coef, p2.w, acc[10]); acc[11] = fmaf(coef, p3.y, acc[11]);
        acc[12] = fmaf(coef, p3.z, acc[12]); acc[13] = fmaf(coef, p3.w, acc[13]);

        if (sp + 1 < NSPN) GSTORE(buf ^ 1)   // in-wave order; no barrier
    }
#undef ISSUE
#undef GSTORE

    // ---- out: DIRECT coalesced stores from registers (no LDS) ----
    float z[14];
    #pragma unroll
    for (int j = 0; j < 14; ++j) z[j] = a[j] * acc[j];

    float* op = out + ubase + s * 14;
    if (s < 3) {
        float4 y0 = make_float4(z[0], z[1], z[2], z[3]);
        float4 y1 = make_float4(z[4], z[5], z[6], z[7]);
        float4 y2 = make_float4(z[8], z[9], z[10], z[11]);
        float2 y3 = make_float2(z[12], z[13]);
        __builtin_memcpy(op,      &y0, 16);
        __builtin_memcpy(op + 4,  &y1, 16);
        __builtin_memcpy(op + 8,  &y2, 16);
        __builtin_memcpy(op + 12, &y3,  8);
    } else {                                  // k 42..48 (7 dwords)
        float4 y0 = make_float4(z[0], z[1], z[2], z[3]);
        float2 y1 = make_float2(z[4], z[5]);
        __builtin_memcpy(op,     &y0, 16);
        __builtin_memcpy(op + 4, &y1,  8);
        op[6] = z[6];
    }
}

extern "C" void kernel_launch(void* const* d_in, const int* in_sizes, int n_in,
                              void* d_out, int out_size, void* d_ws, size_t ws_size,
                              hipStream_t stream) {
    const float* attn  = (const float*)d_in[0];
    const float* sims  = (const float*)d_in[1];
    const int*   sinds = (const int*)d_in[2];
    float*       outp  = (float*)d_out;

    // blocks: b(2) x hh(128) x wseg(8) = 2048, 4 waves each (16 pixels/block)
    const int blocks = BN * HN * (WN / 16);
    attn_rw12<<<blocks, TPB, 0, stream>>>(attn, sims, sinds, outp);
}